// Round 5
// baseline (21.007 us; speedup 1.0000x reference)
//
#include <hip/hip_runtime.h>
#include <math.h>

#define S2 64
#define HH 128
#define WW 128
#define BB 16
#define TIK 0.05f
#define NU 33           // uu = 0..32; uu=1..31 also emit mirror row u = 64-uu
#define NBLK (BB * NU)  // 528 blocks
#define MAGIC1 0x5EEDF00Du
#define MAGIC2 0xC0FFEE42u

// Single dispatch. One block per (b,uu), 256 threads. Last block (bid 527)
// finalizes after consuming publish-flags from the other 527 blocks.
// Flags are EXCHANGED to 0 on consume -> self-resetting across graph replays
// (poison 0xAAAAAAAA != magic; leftover 0 != magic). No grid.sync (R3: ~30us).
__global__ __launch_bounds__(256) void chf_fused(const float* __restrict__ dnn,
                                                 const float* __restrict__ chf,
                                                 float* __restrict__ partials,
                                                 unsigned int* __restrict__ flag1,
                                                 unsigned int* __restrict__ flag2,
                                                 float* __restrict__ out) {
    const int bid = blockIdx.x;
    const int b = bid / NU;
    const int uu = bid - b * NU;     // 0..32
    const int t = threadIdx.x;       // 0..255
    const bool is_final = (bid == NBLK - 1);

    __shared__ float cb[HH], sb[HH];            // cos/sin(fu*(h+0.5))
    __shared__ float a2r[8 * WW], a2i[8 * WW];  // phase-A h-group partials
    __shared__ float crw[WW], ciw[WW];          // stage-A outputs
    __shared__ float prc[256], prs[256], pic[256], pis[256];
    __shared__ float pall[NBLK];                // finalizer gather
    __shared__ float red[BB];

    const float fu = (float)(uu - 32) * TIK;

    // Prefetch chf early so the epilogue doesn't stall on a cold load.
    float2 cf = make_float2(0.f, 0.f), cfm = make_float2(0.f, 0.f);
    if (t < 64) {
        cf = *(const float2*)(chf + ((((size_t)b * S2 + uu) * S2 + t) * 2));
        if (uu >= 1 && uu <= 31)
            cfm = *(const float2*)(chf + ((((size_t)b * S2 + (64 - uu)) * S2 + t) * 2));
    }

    if (t < HH) {
        float s, c;
        sincosf(fu * ((float)t + 0.5f), &s, &c);
        cb[t] = c;
        sb[t] = s;
    }
    __syncthreads();

    // ---- Phase A: 8 h-groups x 16 h each; float4 over 4 w columns ----
    {
        const int hg = t >> 5;          // 0..7
        const int w4 = (t & 31) << 2;   // 0,4,...,124
        const float4* drow = (const float4*)(dnn + (size_t)b * HH * WW);
        float ar0 = 0, ar1 = 0, ar2 = 0, ar3 = 0;
        float ai0 = 0, ai1 = 0, ai2 = 0, ai3 = 0;
#pragma unroll
        for (int j = 0; j < 16; ++j) {
            const int h = hg * 16 + j;
            const float4 d = drow[h * (WW / 4) + (w4 >> 2)];
            const float ch = cb[h], sh = sb[h];
            ar0 = fmaf(ch, d.x, ar0); ai0 = fmaf(sh, d.x, ai0);
            ar1 = fmaf(ch, d.y, ar1); ai1 = fmaf(sh, d.y, ai1);
            ar2 = fmaf(ch, d.z, ar2); ai2 = fmaf(sh, d.z, ai2);
            ar3 = fmaf(ch, d.w, ar3); ai3 = fmaf(sh, d.w, ai3);
        }
        *(float4*)&a2r[hg * WW + w4] = make_float4(ar0, ar1, ar2, ar3);
        *(float4*)&a2i[hg * WW + w4] = make_float4(ai0, ai1, ai2, ai3);
    }
    __syncthreads();

    if (t < WW) {
        float sr = 0, si = 0;
#pragma unroll
        for (int g = 0; g < 8; ++g) {
            sr += a2r[g * WW + t];
            si += a2i[g * WW + t];
        }
        crw[t] = sr;
        ciw[t] = si;
    }
    __syncthreads();

    // ---- Phase B: rotation recurrence, 4 cross-sums per thread ----
    {
        const int v = t & 63;
        const int q = t >> 6;  // quarter 0..3
        const float fv = (float)(v - 32) * TIK;
        float s0, c0, ss, cs;
        sincosf(fv * ((float)(q * 32) + 0.5f), &s0, &c0);  // angle at w = q*32
        sincosf(fv, &ss, &cs);                              // per-step rotation
        float c = c0, s = s0;
        float rc = 0, rs = 0, ic = 0, is_ = 0;
#pragma unroll
        for (int j = 0; j < 32; ++j) {
            const int w = q * 32 + j;
            const float cr = crw[w], ci = ciw[w];
            rc = fmaf(c, cr, rc);
            rs = fmaf(s, cr, rs);
            ic = fmaf(c, ci, ic);
            is_ = fmaf(s, ci, is_);
            const float cn = fmaf(c, cs, -s * ss);
            s = fmaf(s, cs, c * ss);   // uses old c
            c = cn;
        }
        prc[t] = rc; prs[t] = rs; pic[t] = ic; pis[t] = is_;
    }
    __syncthreads();

    // ---- Combine quarters, emit u and mirror 64-u, squared error ----
    float sq = 0.0f;
    if (t < 64) {
        const float rc = prc[t] + prc[t + 64] + prc[t + 128] + prc[t + 192];
        const float rs = prs[t] + prs[t + 64] + prs[t + 128] + prs[t + 192];
        const float ic = pic[t] + pic[t + 64] + pic[t + 128] + pic[t + 192];
        const float is_ = pis[t] + pis[t + 64] + pis[t + 128] + pis[t + 192];

        const float d0 = (rc - is_) - cf.x;   // real(u)
        const float d1 = (rs + ic) - cf.y;    // img(u)
        sq = fmaf(d0, d0, d1 * d1);

        if (uu >= 1 && uu <= 31) {
            const float d2 = (rc + is_) - cfm.x;  // real(64-u)
            const float d3 = (rs - ic) - cfm.y;   // img(64-u)
            sq = fmaf(d2, d2, sq);
            sq = fmaf(d3, d3, sq);
        }
#pragma unroll
        for (int off = 32; off; off >>= 1)
            sq += __shfl_down(sq, off, 64);
    }

    // ---- Publish (non-final blocks) ----
    if (!is_final) {
        if (t == 0) {
            __hip_atomic_store(&partials[bid], sq, __ATOMIC_RELAXED, __HIP_MEMORY_SCOPE_AGENT);
            __hip_atomic_store(&flag1[bid], MAGIC1, __ATOMIC_RELEASE, __HIP_MEMORY_SCOPE_AGENT);
            __hip_atomic_store(&flag2[bid], MAGIC2, __ATOMIC_RELEASE, __HIP_MEMORY_SCOPE_AGENT);
        }
        return;
    }

    // ---- Finalizer (bid == NBLK-1): consume flags, reduce, write out ----
    for (int i = t; i < NBLK - 1; i += 256) {
        while (__hip_atomic_exchange(&flag1[i], 0u, __ATOMIC_ACQUIRE,
                                     __HIP_MEMORY_SCOPE_AGENT) != MAGIC1)
            __builtin_amdgcn_s_sleep(1);
        while (__hip_atomic_exchange(&flag2[i], 0u, __ATOMIC_ACQUIRE,
                                     __HIP_MEMORY_SCOPE_AGENT) != MAGIC2)
            __builtin_amdgcn_s_sleep(1);
        pall[i] = __hip_atomic_load(&partials[i], __ATOMIC_RELAXED, __HIP_MEMORY_SCOPE_AGENT);
    }
    if (t == 0) pall[NBLK - 1] = sq;  // own partial, never leaves the block
    __syncthreads();

    if (t < BB) {
        float acc = 0;
#pragma unroll
        for (int i = 0; i < NU; ++i) acc += pall[t * NU + i];
        red[t] = sqrtf(acc);
    }
    __syncthreads();
    if (t == 0) {
        float tot = 0;
#pragma unroll
        for (int i = 0; i < BB; ++i) tot += red[i];
        out[0] = tot * (TIK / (float)BB);
    }
}

extern "C" void kernel_launch(void* const* d_in, const int* in_sizes, int n_in,
                              void* d_out, int out_size, void* d_ws, size_t ws_size,
                              hipStream_t stream) {
    const float* dnn = (const float*)d_in[0];  // (16,128,128) f32
    const float* chf = (const float*)d_in[1];  // (16,64,64,2) f32
    float* out = (float*)d_out;                // scalar f32

    float* partials = (float*)d_ws;                        // [0, NBLK)
    unsigned int* flag1 = (unsigned int*)d_ws + NBLK;      // [NBLK, 2*NBLK)
    unsigned int* flag2 = (unsigned int*)d_ws + 2 * NBLK;  // [2*NBLK, 3*NBLK)

    chf_fused<<<dim3(NBLK), dim3(256), 0, stream>>>(dnn, chf, partials,
                                                    flag1, flag2, out);
}

// Round 6
// 11.470 us; speedup vs baseline: 1.8315x; 1.8315x over previous
//
#include <hip/hip_runtime.h>
#include <math.h>

#define S2 64
#define HH 128
#define WW 128
#define BB 16
#define TIK 0.05f
#define NU 33           // uu = 0..32; uu=1..31 also emit mirror row u = 64-uu
#define NBLK (BB * NU)  // 528 blocks

// complex rotate: (c,s) *= (cr,sr)
#define ROT(c, s, cr, sr)                    \
    {                                        \
        const float _cn = fmaf(c, cr, -(s) * (sr)); \
        s = fmaf(s, cr, (c) * (sr));         \
        c = _cn;                             \
    }

// One block per (b,uu), 256 threads, two dispatches (R3/R5 lesson: any
// in-kernel cross-XCD handoff costs more than a 2nd dispatch).
// All trig via in-register rotator recurrences seeded with HW __sinf/__cosf.
__global__ __launch_bounds__(256) void chf_main(const float* __restrict__ dnn,
                                                const float* __restrict__ chf,
                                                float* __restrict__ partials) {
    const int bid = blockIdx.x;
    const int b = bid / NU;
    const int uu = bid - b * NU;     // 0..32
    const int t = threadIdx.x;       // 0..255

    __shared__ float a2r[8 * WW], a2i[8 * WW];  // phase-A h-group partials
    __shared__ float crw[WW], ciw[WW];          // stage-A outputs
    __shared__ float prc[256], prs[256], pic[256], pis[256];

    const float fu = (float)(uu - 32) * TIK;

    // Prefetch chf early (epilogue operand).
    float2 cf = make_float2(0.f, 0.f), cfm = make_float2(0.f, 0.f);
    if (t < 64) {
        cf = *(const float2*)(chf + ((((size_t)b * S2 + uu) * S2 + t) * 2));
        if (uu >= 1 && uu <= 31)
            cfm = *(const float2*)(chf + ((((size_t)b * S2 + (64 - uu)) * S2 + t) * 2));
    }

    // ---- Phase A: 8 h-groups x 16 h; 2 rotators (step 2*fu), no LDS trig ----
    {
        const int hg = t >> 5;          // 0..7
        const int w4 = (t & 31) << 2;   // 0,4,...,124
        const float4* drow = (const float4*)(dnn + (size_t)b * HH * WW);

        const float a0 = fu * ((float)(hg * 16) + 0.5f);
        float c0 = __cosf(a0), s0 = __sinf(a0);          // h = hg*16 (even j)
        const float cfu = __cosf(fu), sfu = __sinf(fu);
        float c1 = c0, s1 = s0;
        ROT(c1, s1, cfu, sfu);                           // h = hg*16+1 (odd j)
        const float c2s = fmaf(cfu, cfu, -sfu * sfu);    // cos(2fu)
        const float s2s = 2.0f * sfu * cfu;              // sin(2fu)

        float ar0 = 0, ar1 = 0, ar2 = 0, ar3 = 0;
        float ai0 = 0, ai1 = 0, ai2 = 0, ai3 = 0;
#pragma unroll
        for (int j = 0; j < 8; ++j) {
            const int h = hg * 16 + 2 * j;
            const float4 d0 = drow[h * (WW / 4) + (w4 >> 2)];
            const float4 d1 = drow[(h + 1) * (WW / 4) + (w4 >> 2)];
            ar0 = fmaf(c0, d0.x, ar0); ai0 = fmaf(s0, d0.x, ai0);
            ar1 = fmaf(c0, d0.y, ar1); ai1 = fmaf(s0, d0.y, ai1);
            ar2 = fmaf(c0, d0.z, ar2); ai2 = fmaf(s0, d0.z, ai2);
            ar3 = fmaf(c0, d0.w, ar3); ai3 = fmaf(s0, d0.w, ai3);
            ar0 = fmaf(c1, d1.x, ar0); ai0 = fmaf(s1, d1.x, ai0);
            ar1 = fmaf(c1, d1.y, ar1); ai1 = fmaf(s1, d1.y, ai1);
            ar2 = fmaf(c1, d1.z, ar2); ai2 = fmaf(s1, d1.z, ai2);
            ar3 = fmaf(c1, d1.w, ar3); ai3 = fmaf(s1, d1.w, ai3);
            ROT(c0, s0, c2s, s2s);
            ROT(c1, s1, c2s, s2s);
        }
        *(float4*)&a2r[hg * WW + w4] = make_float4(ar0, ar1, ar2, ar3);
        *(float4*)&a2i[hg * WW + w4] = make_float4(ai0, ai1, ai2, ai3);
    }
    __syncthreads();

    if (t < WW) {
        float sr = 0, si = 0;
#pragma unroll
        for (int g = 0; g < 8; ++g) {
            sr += a2r[g * WW + t];
            si += a2i[g * WW + t];
        }
        crw[t] = sr;
        ciw[t] = si;
    }
    __syncthreads();

    // ---- Phase B: 4 rotators (step 4*fv), serial chain 8 steps ----
    {
        const int v = t & 63;
        const int q = t >> 6;  // quarter 0..3
        const int w0 = q * 32;
        const float fv = (float)(v - 32) * TIK;

        const float a0 = fv * ((float)w0 + 0.5f);
        float c0 = __cosf(a0), s0 = __sinf(a0);
        const float cfv = __cosf(fv), sfv = __sinf(fv);
        float c1 = c0, s1 = s0; ROT(c1, s1, cfv, sfv);
        float c2 = c1, s2 = s1; ROT(c2, s2, cfv, sfv);
        float c3 = c2, s3 = s2; ROT(c3, s3, cfv, sfv);
        const float c2f = fmaf(cfv, cfv, -sfv * sfv);  // cos(2fv)
        const float s2f = 2.0f * sfv * cfv;            // sin(2fv)
        const float c4f = fmaf(c2f, c2f, -s2f * s2f);  // cos(4fv)
        const float s4f = 2.0f * s2f * c2f;            // sin(4fv)

        float rc = 0, rs = 0, ic = 0, is_ = 0;
#pragma unroll
        for (int j = 0; j < 8; ++j) {
            const int w = w0 + 4 * j;
            float cr, ci;
            cr = crw[w];     ci = ciw[w];
            rc = fmaf(c0, cr, rc); rs = fmaf(s0, cr, rs);
            ic = fmaf(c0, ci, ic); is_ = fmaf(s0, ci, is_);
            cr = crw[w + 1]; ci = ciw[w + 1];
            rc = fmaf(c1, cr, rc); rs = fmaf(s1, cr, rs);
            ic = fmaf(c1, ci, ic); is_ = fmaf(s1, ci, is_);
            cr = crw[w + 2]; ci = ciw[w + 2];
            rc = fmaf(c2, cr, rc); rs = fmaf(s2, cr, rs);
            ic = fmaf(c2, ci, ic); is_ = fmaf(s2, ci, is_);
            cr = crw[w + 3]; ci = ciw[w + 3];
            rc = fmaf(c3, cr, rc); rs = fmaf(s3, cr, rs);
            ic = fmaf(c3, ci, ic); is_ = fmaf(s3, ci, is_);
            ROT(c0, s0, c4f, s4f);
            ROT(c1, s1, c4f, s4f);
            ROT(c2, s2, c4f, s4f);
            ROT(c3, s3, c4f, s4f);
        }
        prc[t] = rc; prs[t] = rs; pic[t] = ic; pis[t] = is_;
    }
    __syncthreads();

    // ---- Combine quarters, emit u and mirror 64-u, squared error ----
    if (t < 64) {
        const float rc = prc[t] + prc[t + 64] + prc[t + 128] + prc[t + 192];
        const float rs = prs[t] + prs[t + 64] + prs[t + 128] + prs[t + 192];
        const float ic = pic[t] + pic[t + 64] + pic[t + 128] + pic[t + 192];
        const float is_ = pis[t] + pis[t + 64] + pis[t + 128] + pis[t + 192];

        const float d0 = (rc - is_) - cf.x;   // real(u)
        const float d1 = (rs + ic) - cf.y;    // img(u)
        float sq = fmaf(d0, d0, d1 * d1);

        if (uu >= 1 && uu <= 31) {
            const float d2 = (rc + is_) - cfm.x;  // real(64-u)
            const float d3 = (rs - ic) - cfm.y;   // img(64-u)
            sq = fmaf(d2, d2, sq);
            sq = fmaf(d3, d3, sq);
        }
#pragma unroll
        for (int off = 32; off; off >>= 1)
            sq += __shfl_down(sq, off, 64);
        if (t == 0) partials[bid] = sq;
    }
}

// 1 block x 1024 threads: wave b reduces the 33 partials of batch b.
__global__ __launch_bounds__(1024) void chf_final(const float* __restrict__ partials,
                                                  float* __restrict__ out) {
    const int t = threadIdx.x;   // 0..1023
    const int b = t >> 6;        // wave index = batch
    const int l = t & 63;
    __shared__ float red[BB];
    float v = (l < NU) ? partials[b * NU + l] : 0.0f;
#pragma unroll
    for (int off = 32; off; off >>= 1)
        v += __shfl_down(v, off, 64);
    if (l == 0) red[b] = sqrtf(v);
    __syncthreads();
    if (t == 0) {
        float acc = 0;
#pragma unroll
        for (int i = 0; i < BB; ++i) acc += red[i];
        out[0] = acc * (TIK / (float)BB);
    }
}

extern "C" void kernel_launch(void* const* d_in, const int* in_sizes, int n_in,
                              void* d_out, int out_size, void* d_ws, size_t ws_size,
                              hipStream_t stream) {
    const float* dnn = (const float*)d_in[0];  // (16,128,128) f32
    const float* chf = (const float*)d_in[1];  // (16,64,64,2) f32
    float* out = (float*)d_out;                // scalar f32
    float* partials = (float*)d_ws;            // NBLK floats, fully overwritten

    chf_main<<<dim3(NBLK), dim3(256), 0, stream>>>(dnn, chf, partials);
    chf_final<<<dim3(1), dim3(1024), 0, stream>>>(partials, out);
}